// Round 1
// baseline (999.936 us; speedup 1.0000x reference)
//
#include <hip/hip_runtime.h>
#include <math.h>

#define Bn 8
#define Cn 64
#define Hn 128
#define Wn 128
#define HWn (Hn * Wn)
#define Kn 9

// ---------------------------------------------------------------------------
// Kernel 1: 3x3 conv 64 -> 27 channels (offset/mask generator).
// Output layout: offmask[(b*9+k)*3 + comp][h][w], comp: 0=off_y, 1=off_x, 2=mask
// mask channel has 2*sigmoid applied.
// Grid: (16,16,8) tiles of 8x8 pixels, 256 threads.
// ---------------------------------------------------------------------------
__global__ __launch_bounds__(256) void k_conv_om(
    const float* __restrict__ x, const float* __restrict__ w_om,
    const float* __restrict__ b_om, float* __restrict__ offmask) {
  // stride 12 in last dim: 64-lane pixel reads land 2 lanes/bank (free)
  __shared__ float tile[64][10][12];
  const int b = blockIdx.z;
  const int ty0 = blockIdx.y * 8, tx0 = blockIdx.x * 8;
  const int tid = threadIdx.x;
  const float* xb = x + b * Cn * HWn;

  for (int i = tid; i < 64 * 100; i += 256) {
    int cin = i / 100, r = i - cin * 100;
    int iy = r / 10, ix = r - iy * 10;
    int gy = ty0 + iy - 1, gx = tx0 + ix - 1;
    float v = 0.f;
    if (gy >= 0 && gy < Hn && gx >= 0 && gx < Wn)
      v = xb[cin * HWn + gy * Wn + gx];
    tile[cin][iy][ix] = v;
  }
  __syncthreads();

  const int p = tid & 63, cg = tid >> 6;      // 64 pixels x 4 channel-groups
  const int py = p >> 3, px = p & 7;
  const int co0 = cg * 7;
  const int nco = (cg == 3) ? 6 : 7;          // 27 = 7+7+7+6

  float acc[7];
#pragma unroll
  for (int j = 0; j < 7; ++j) acc[j] = 0.f;

  for (int cin = 0; cin < 64; ++cin) {
#pragma unroll
    for (int ky = 0; ky < 3; ++ky) {
      float t0 = tile[cin][py + ky][px + 0];
      float t1 = tile[cin][py + ky][px + 1];
      float t2 = tile[cin][py + ky][px + 2];
      const float* wp = w_om + (co0 * 64 + cin) * 9 + ky * 3;
#pragma unroll
      for (int j = 0; j < 7; ++j) {
        if (j < nco) {  // wave-uniform (cg uniform per wave)
          acc[j] += wp[j * 576 + 0] * t0 + wp[j * 576 + 1] * t1 +
                    wp[j * 576 + 2] * t2;
        }
      }
    }
  }

  const int gy = ty0 + py, gx = tx0 + px;
  for (int j = 0; j < nco; ++j) {
    int co = co0 + j;
    float v = acc[j] + b_om[co];
    int k, comp;
    if (co < 18) {
      k = co >> 1; comp = co & 1;
    } else {
      k = co - 18; comp = 2;
      v = 2.f / (1.f + expf(-v));   // 2*sigmoid
    }
    offmask[((b * Kn + k) * 3 + comp) * HWn + gy * Wn + gx] = v;
  }
}

// ---------------------------------------------------------------------------
// Kernel 2: modulated deformable conv 64->64 + bias + leaky-ReLU -> act.
// Workgroup: 64 pixels (one half-row) x 64 cout. cin chunked by 16.
// Grid: (2,128,8), 256 threads.
// ---------------------------------------------------------------------------
__global__ __launch_bounds__(256) void k_deform(
    const float* __restrict__ x, const float* __restrict__ offmask,
    const float* __restrict__ w_dc, const float* __restrict__ b_dc,
    float* __restrict__ act) {
  __shared__ float val[144][64];     // (cin16 x 9) x 64 px = 36.9 KB
  __shared__ int   sb[4][9][64];     // 4 corner flat spatial offsets
  __shared__ float sw[4][9][64];     // 4 corner weights (validity*mask folded)

  const int b = blockIdx.z, h = blockIdx.y, w0 = blockIdx.x * 64;
  const int tid = threadIdx.x;
  const float* xb = x + b * Cn * HWn;

  // ---- phase A: per (k, pixel) bilinear params ----
  for (int i = tid; i < 576; i += 256) {
    int k = i >> 6, p = i & 63;
    const float* om = offmask + (b * Kn + k) * 3 * HWn + h * Wn + w0 + p;
    float offy = om[0];
    float offx = om[HWn];
    float m    = om[2 * HWn];
    float py = (float)(h - 1 + (k / 3)) + offy;
    float px = (float)(w0 + p - 1 + (k % 3)) + offx;
    float fy = floorf(py), fx = floorf(px);
    float ly = py - fy, lx = px - fx;
    int iy0 = (int)fy, ix0 = (int)fx;
    int iy1 = iy0 + 1, ix1 = ix0 + 1;
    bool vy0 = (iy0 >= 0) && (iy0 < Hn);
    bool vy1 = (iy1 >= 0) && (iy1 < Hn);
    bool vx0 = (ix0 >= 0) && (ix0 < Wn);
    bool vx1 = (ix1 >= 0) && (ix1 < Wn);
    int cy0 = min(max(iy0, 0), Hn - 1), cy1 = min(max(iy1, 0), Hn - 1);
    int cx0 = min(max(ix0, 0), Wn - 1), cx1 = min(max(ix1, 0), Wn - 1);
    sb[0][k][p] = cy0 * Wn + cx0;
    sb[1][k][p] = cy0 * Wn + cx1;
    sb[2][k][p] = cy1 * Wn + cx0;
    sb[3][k][p] = cy1 * Wn + cx1;
    sw[0][k][p] = (vy0 && vx0) ? (1.f - ly) * (1.f - lx) * m : 0.f;
    sw[1][k][p] = (vy0 && vx1) ? (1.f - ly) * lx * m : 0.f;
    sw[2][k][p] = (vy1 && vx0) ? ly * (1.f - lx) * m : 0.f;
    sw[3][k][p] = (vy1 && vx1) ? ly * lx * m : 0.f;
  }

  const int pg = tid & 15, cg = tid >> 4;   // 16 px-groups x 16 cout-groups
  float acc[4][4];
#pragma unroll
  for (int j = 0; j < 4; ++j)
#pragma unroll
    for (int q = 0; q < 4; ++q) acc[j][q] = 0.f;

  for (int cc = 0; cc < 4; ++cc) {
    __syncthreads();  // protect val from previous GEMM readers (and phase A)
    // ---- fill: bilinear-sample 16 cin x 9 k x 64 px ----
    for (int i = tid; i < 144 * 64; i += 256) {
      int ck = i >> 6, p = i & 63;
      int ci = ck / 9, k = ck - ci * 9;
      const float* xc = xb + (cc * 16 + ci) * HWn;
      float v = sw[0][k][p] * xc[sb[0][k][p]]
              + sw[1][k][p] * xc[sb[1][k][p]]
              + sw[2][k][p] * xc[sb[2][k][p]]
              + sw[3][k][p] * xc[sb[3][k][p]];
      val[ck][p] = v;
    }
    __syncthreads();
    // ---- GEMM partial: 4 cout x 4 px per thread over 144 ck ----
    const float* wb = w_dc + cc * 144;
    for (int ckl = 0; ckl < 144; ckl += 4) {
      float wv[4][4];
#pragma unroll
      for (int j = 0; j < 4; ++j) {
        float4 t = *(const float4*)(wb + (cg * 4 + j) * 576 + ckl);
        wv[j][0] = t.x; wv[j][1] = t.y; wv[j][2] = t.z; wv[j][3] = t.w;
      }
#pragma unroll
      for (int u = 0; u < 4; ++u) {
        float4 v4 = *(const float4*)&val[ckl + u][pg * 4];
#pragma unroll
        for (int j = 0; j < 4; ++j) {
          acc[j][0] += wv[j][u] * v4.x;
          acc[j][1] += wv[j][u] * v4.y;
          acc[j][2] += wv[j][u] * v4.z;
          acc[j][3] += wv[j][u] * v4.w;
        }
      }
    }
  }

  // ---- epilogue: bias + leaky ReLU ----
#pragma unroll
  for (int j = 0; j < 4; ++j) {
    int co = cg * 4 + j;
    float bias = b_dc[co];
    float4 o;
    float v;
    v = acc[j][0] + bias; o.x = v > 0.f ? v : 0.2f * v;
    v = acc[j][1] + bias; o.y = v > 0.f ? v : 0.2f * v;
    v = acc[j][2] + bias; o.z = v > 0.f ? v : 0.2f * v;
    v = acc[j][3] + bias; o.w = v > 0.f ? v : 0.2f * v;
    *(float4*)&act[((b * Cn + co) * Hn + h) * Wn + w0 + pg * 4] = o;
  }
}

// ---------------------------------------------------------------------------
// Kernel 3: 3x3 conv 64->64 on act + bias + residual x -> out.
// Same implicit-GEMM skeleton as kernel 2; im2col is shifted reads.
// Grid: (2,128,8), 256 threads.
// ---------------------------------------------------------------------------
__global__ __launch_bounds__(256) void k_conv_out(
    const float* __restrict__ actp, const float* __restrict__ w_c,
    const float* __restrict__ b_c, const float* __restrict__ x,
    float* __restrict__ out) {
  __shared__ float val[144][64];

  const int b = blockIdx.z, h = blockIdx.y, w0 = blockIdx.x * 64;
  const int tid = threadIdx.x;
  const float* ab = actp + b * Cn * HWn;
  const int pg = tid & 15, cg = tid >> 4;

  float acc[4][4];
#pragma unroll
  for (int j = 0; j < 4; ++j)
#pragma unroll
    for (int q = 0; q < 4; ++q) acc[j][q] = 0.f;

  for (int cc = 0; cc < 4; ++cc) {
    __syncthreads();
    for (int i = tid; i < 144 * 64; i += 256) {
      int ck = i >> 6, p = i & 63;
      int ci = ck / 9, k = ck - ci * 9;
      int ky = k / 3, kx = k - ky * 3;
      int gy = h + ky - 1, gx = w0 + p + kx - 1;
      float v = 0.f;
      if (gy >= 0 && gy < Hn && gx >= 0 && gx < Wn)
        v = ab[(cc * 16 + ci) * HWn + gy * Wn + gx];
      val[ck][p] = v;
    }
    __syncthreads();
    const float* wb = w_c + cc * 144;
    for (int ckl = 0; ckl < 144; ckl += 4) {
      float wv[4][4];
#pragma unroll
      for (int j = 0; j < 4; ++j) {
        float4 t = *(const float4*)(wb + (cg * 4 + j) * 576 + ckl);
        wv[j][0] = t.x; wv[j][1] = t.y; wv[j][2] = t.z; wv[j][3] = t.w;
      }
#pragma unroll
      for (int u = 0; u < 4; ++u) {
        float4 v4 = *(const float4*)&val[ckl + u][pg * 4];
#pragma unroll
        for (int j = 0; j < 4; ++j) {
          acc[j][0] += wv[j][u] * v4.x;
          acc[j][1] += wv[j][u] * v4.y;
          acc[j][2] += wv[j][u] * v4.z;
          acc[j][3] += wv[j][u] * v4.w;
        }
      }
    }
  }

#pragma unroll
  for (int j = 0; j < 4; ++j) {
    int co = cg * 4 + j;
    float bias = b_c[co];
    int base = ((b * Cn + co) * Hn + h) * Wn + w0 + pg * 4;
    float4 xr = *(const float4*)&x[base];
    float4 o;
    o.x = acc[j][0] + bias + xr.x;
    o.y = acc[j][1] + bias + xr.y;
    o.z = acc[j][2] + bias + xr.z;
    o.w = acc[j][3] + bias + xr.w;
    *(float4*)&out[base] = o;
  }
}

// ---------------------------------------------------------------------------
extern "C" void kernel_launch(void* const* d_in, const int* in_sizes, int n_in,
                              void* d_out, int out_size, void* d_ws,
                              size_t ws_size, hipStream_t stream) {
  const float* x    = (const float*)d_in[0];
  const float* w_om = (const float*)d_in[1];
  const float* b_om = (const float*)d_in[2];
  const float* w_dc = (const float*)d_in[3];
  const float* b_dc = (const float*)d_in[4];
  const float* w_c  = (const float*)d_in[5];
  const float* b_c  = (const float*)d_in[6];
  float* out = (float*)d_out;

  // workspace: offmask (B*9*3*HW floats = 14.2 MB) then act (B*64*HW = 16.8 MB)
  float* offmask = (float*)d_ws;
  float* act = offmask + (size_t)Bn * Kn * 3 * HWn;

  k_conv_om<<<dim3(16, 16, Bn), 256, 0, stream>>>(x, w_om, b_om, offmask);
  k_deform<<<dim3(2, Hn, Bn), 256, 0, stream>>>(x, offmask, w_dc, b_dc, act);
  k_conv_out<<<dim3(2, Hn, Bn), 256, 0, stream>>>(act, w_c, b_c, x, out);
}

// Round 2
// 252.110 us; speedup vs baseline: 3.9663x; 3.9663x over previous
//
#include <hip/hip_runtime.h>
#include <math.h>

#define Bn 8
#define Cn 64
#define Hn 128
#define Wn 128
#define HWn (Hn * Wn)
#define Kn 9

typedef __attribute__((ext_vector_type(8))) short short8;
typedef __attribute__((ext_vector_type(4))) float floatx4;

__device__ __forceinline__ float bf2f(short s) {
  return __uint_as_float(((unsigned)(unsigned short)s) << 16);
}
__device__ __forceinline__ short f2bf(float f) {
  unsigned u = __float_as_uint(f);
  u += 0x7fff + ((u >> 16) & 1);  // RNE
  return (short)(u >> 16);
}

// ---------------------------------------------------------------------------
// Prep 1: weights fp32 [cout][cin][kk] -> bf16 [row][kk*64+cin].
// rows 0..31: w_om (27 real, 5 zero-pad), 32..95: w_dc, 96..159: w_c.
// ---------------------------------------------------------------------------
__global__ __launch_bounds__(256) void k_prep_w(
    const float* __restrict__ w_om, const float* __restrict__ w_dc,
    const float* __restrict__ w_c, short* __restrict__ wt) {
  int idx = blockIdx.x * 256 + threadIdx.x;
  if (idx >= 160 * 576) return;
  int row = idx / 576, k = idx - row * 576;
  int kk = k >> 6, cin = k & 63;
  float v;
  if (row < 32)
    v = (row < 27) ? w_om[(row * 64 + cin) * 9 + kk] : 0.f;
  else if (row < 96)
    v = w_dc[((row - 32) * 64 + cin) * 9 + kk];
  else
    v = w_c[((row - 96) * 64 + cin) * 9 + kk];
  wt[idx] = f2bf(v);
}

// ---------------------------------------------------------------------------
// Prep 2: x fp32 NCHW -> bf16 channels-last [b][h][w][64].
// ---------------------------------------------------------------------------
__global__ __launch_bounds__(256) void k_prep_x(const float* __restrict__ x,
                                                short* __restrict__ xT) {
  __shared__ float tile[64][129];
  const int h = blockIdx.x, b = blockIdx.y;
  const int tid = threadIdx.x;
  const float* xb = x + (size_t)b * 64 * HWn + h * Wn;
  for (int i = tid; i < 8192; i += 256) {
    int c = i >> 7, w = i & 127;
    tile[c][w] = xb[c * HWn + w];
  }
  __syncthreads();
  short* dst = xT + ((size_t)(b * Hn + h) * Wn) * 64;
  for (int i = tid; i < 2048; i += 256) {
    int w = i >> 4, c4 = (i & 15) * 4;
    short4 o;
    o.x = f2bf(tile[c4 + 0][w]);
    o.y = f2bf(tile[c4 + 1][w]);
    o.z = f2bf(tile[c4 + 2][w]);
    o.w = f2bf(tile[c4 + 3][w]);
    *(short4*)(dst + (size_t)w * 64 + c4) = o;
  }
}

// ---------------------------------------------------------------------------
// Kernel 1: conv_om via MFMA. M=32 (27 real cout), N=64 px, K=576.
// Writes offmask fp32 [(b*9+k)*3+comp][h][w], mask = 2*sigmoid.
// Grid (2,128,8), 256 threads.
// ---------------------------------------------------------------------------
__global__ __launch_bounds__(256) void k_conv_om(
    const short* __restrict__ xT, const short* __restrict__ wt_om,
    const float* __restrict__ b_om, float* __restrict__ offmask) {
  __shared__ short val[64][296];  // [px][kk*32+cin_local], pad 288->296
  const int b = blockIdx.z, h = blockIdx.y, w0 = blockIdx.x * 64;
  const int tid = threadIdx.x;
  const int wave = tid >> 6, lane = tid & 63, quad = lane >> 4, lr = lane & 15;
  const short* xTb = xT + (size_t)b * HWn * 64;

  floatx4 zf = {0.f, 0.f, 0.f, 0.f};
  floatx4 acc0 = zf, acc1 = zf;
  const int m0 = (wave & 1) * 16;   // 2 m-tiles cover M=32
  const int n0 = (wave >> 1) * 32;  // 2 n-tiles each

  for (int cc = 0; cc < 2; ++cc) {
    __syncthreads();
    for (int j = tid; j < 2304; j += 256) {
      int c8 = (j & 3) * 8;
      int px = (j >> 2) & 63;
      int kk = j >> 8;
      int ky = kk / 3, kx = kk - ky * 3;
      int gy = h + ky - 1, gx = w0 + px + kx - 1;
      short8 v = {0, 0, 0, 0, 0, 0, 0, 0};
      if (gy >= 0 && gy < Hn && gx >= 0 && gx < Wn)
        v = *(const short8*)(xTb + (size_t)(gy * Wn + gx) * 64 + cc * 32 + c8);
      *(short8*)&val[px][kk * 32 + c8] = v;
    }
    __syncthreads();
    const short* wbase = wt_om + cc * 32 + quad * 8;
#pragma unroll
    for (int kk = 0; kk < 9; ++kk) {
      short8 a = *(const short8*)(wbase + (m0 + lr) * 576 + kk * 64);
      short8 bf0 = *(const short8*)&val[n0 + lr][kk * 32 + quad * 8];
      short8 bf1 = *(const short8*)&val[n0 + 16 + lr][kk * 32 + quad * 8];
      acc0 = __builtin_amdgcn_mfma_f32_16x16x32_bf16(a, bf0, acc0, 0, 0, 0);
      acc1 = __builtin_amdgcn_mfma_f32_16x16x32_bf16(a, bf1, acc1, 0, 0, 0);
    }
  }

  float* om_b = offmask + (size_t)b * Kn * 3 * HWn + h * Wn + w0;
#pragma unroll
  for (int nt = 0; nt < 2; ++nt) {
    floatx4 a = nt ? acc1 : acc0;
    int px = n0 + nt * 16 + lr;
#pragma unroll
    for (int r = 0; r < 4; ++r) {
      int cout = m0 + quad * 4 + r;
      if (cout < 27) {
        float v = a[r] + b_om[cout];
        int k, comp;
        if (cout < 18) {
          k = cout >> 1;
          comp = cout & 1;
        } else {
          k = cout - 18;
          comp = 2;
          v = 2.f / (1.f + expf(-v));
        }
        om_b[(size_t)(k * 3 + comp) * HWn + px] = v;
      }
    }
  }
}

// ---------------------------------------------------------------------------
// Kernel 2: modulated deformable conv via MFMA. M=64, N=64 px, K=576.
// Bilinear fill from channels-last bf16 xT; epilogue bias+leakyReLU ->
// actT bf16 channels-last.
// Grid (2,128,8), 256 threads.
// ---------------------------------------------------------------------------
__global__ __launch_bounds__(256) void k_deform(
    const short* __restrict__ xT, const float* __restrict__ offmask,
    const short* __restrict__ wt_dc, const float* __restrict__ b_dc,
    short* __restrict__ actT) {
  __shared__ short val[64][296];
  __shared__ int sb[4][9][64];    // corner spatial flat idx
  __shared__ float sw[4][9][64];  // corner weight (validity*mask folded)
  const int b = blockIdx.z, h = blockIdx.y, w0 = blockIdx.x * 64;
  const int tid = threadIdx.x;
  const int wave = tid >> 6, lane = tid & 63, quad = lane >> 4, lr = lane & 15;
  const short* xTb = xT + (size_t)b * HWn * 64;

  // phase A: bilinear params per (k, px)
  for (int i = tid; i < 576; i += 256) {
    int k = i >> 6, p = i & 63;
    const float* om = offmask + (size_t)(b * Kn + k) * 3 * HWn + h * Wn + w0 + p;
    float offy = om[0];
    float offx = om[HWn];
    float m = om[2 * HWn];
    float py = (float)(h - 1 + (k / 3)) + offy;
    float px_ = (float)(w0 + p - 1 + (k % 3)) + offx;
    float fy = floorf(py), fx = floorf(px_);
    float ly = py - fy, lx = px_ - fx;
    int iy0 = (int)fy, ix0 = (int)fx;
    int iy1 = iy0 + 1, ix1 = ix0 + 1;
    bool vy0 = (iy0 >= 0) && (iy0 < Hn);
    bool vy1 = (iy1 >= 0) && (iy1 < Hn);
    bool vx0 = (ix0 >= 0) && (ix0 < Wn);
    bool vx1 = (ix1 >= 0) && (ix1 < Wn);
    int cy0 = min(max(iy0, 0), Hn - 1), cy1 = min(max(iy1, 0), Hn - 1);
    int cx0 = min(max(ix0, 0), Wn - 1), cx1 = min(max(ix1, 0), Wn - 1);
    sb[0][k][p] = cy0 * Wn + cx0;
    sb[1][k][p] = cy0 * Wn + cx1;
    sb[2][k][p] = cy1 * Wn + cx0;
    sb[3][k][p] = cy1 * Wn + cx1;
    sw[0][k][p] = (vy0 && vx0) ? (1.f - ly) * (1.f - lx) * m : 0.f;
    sw[1][k][p] = (vy0 && vx1) ? (1.f - ly) * lx * m : 0.f;
    sw[2][k][p] = (vy1 && vx0) ? ly * (1.f - lx) * m : 0.f;
    sw[3][k][p] = (vy1 && vx1) ? ly * lx * m : 0.f;
  }

  floatx4 zf = {0.f, 0.f, 0.f, 0.f};
  floatx4 acc[2][2] = {{zf, zf}, {zf, zf}};
  const int m0 = (wave & 1) * 32;
  const int n0 = (wave >> 1) * 32;

  for (int cc = 0; cc < 2; ++cc) {
    __syncthreads();
    for (int j = tid; j < 2304; j += 256) {
      int c8 = (j & 3) * 8;
      int px = (j >> 2) & 63;
      int kk = j >> 8;
      int a0 = sb[0][kk][px], a1 = sb[1][kk][px];
      int a2 = sb[2][kk][px], a3 = sb[3][kk][px];
      float u0 = sw[0][kk][px], u1 = sw[1][kk][px];
      float u2 = sw[2][kk][px], u3 = sw[3][kk][px];
      int cb = cc * 32 + c8;
      short8 q0 = *(const short8*)(xTb + (size_t)a0 * 64 + cb);
      short8 q1 = *(const short8*)(xTb + (size_t)a1 * 64 + cb);
      short8 q2 = *(const short8*)(xTb + (size_t)a2 * 64 + cb);
      short8 q3 = *(const short8*)(xTb + (size_t)a3 * 64 + cb);
      short8 o;
#pragma unroll
      for (int e = 0; e < 8; ++e) {
        float f = u0 * bf2f(q0[e]) + u1 * bf2f(q1[e]) +
                  u2 * bf2f(q2[e]) + u3 * bf2f(q3[e]);
        o[e] = f2bf(f);
      }
      *(short8*)&val[px][kk * 32 + c8] = o;
    }
    __syncthreads();
    const short* wbase = wt_dc + cc * 32 + quad * 8;
#pragma unroll
    for (int kk = 0; kk < 9; ++kk) {
      short8 a0 = *(const short8*)(wbase + (m0 + lr) * 576 + kk * 64);
      short8 a1 = *(const short8*)(wbase + (m0 + 16 + lr) * 576 + kk * 64);
      short8 bf0 = *(const short8*)&val[n0 + lr][kk * 32 + quad * 8];
      short8 bf1 = *(const short8*)&val[n0 + 16 + lr][kk * 32 + quad * 8];
      acc[0][0] = __builtin_amdgcn_mfma_f32_16x16x32_bf16(a0, bf0, acc[0][0], 0, 0, 0);
      acc[0][1] = __builtin_amdgcn_mfma_f32_16x16x32_bf16(a0, bf1, acc[0][1], 0, 0, 0);
      acc[1][0] = __builtin_amdgcn_mfma_f32_16x16x32_bf16(a1, bf0, acc[1][0], 0, 0, 0);
      acc[1][1] = __builtin_amdgcn_mfma_f32_16x16x32_bf16(a1, bf1, acc[1][1], 0, 0, 0);
    }
  }

  // epilogue: bias + leaky ReLU -> actT bf16 [b][h][w][c]
  short* ab = actT + ((size_t)(b * Hn + h) * Wn) * 64;
#pragma unroll
  for (int mt = 0; mt < 2; ++mt) {
#pragma unroll
    for (int nt = 0; nt < 2; ++nt) {
      int px = n0 + nt * 16 + lr;
      int c0 = m0 + mt * 16 + quad * 4;
      short4 o;
      float v;
      v = acc[mt][nt][0] + b_dc[c0 + 0]; o.x = f2bf(v > 0.f ? v : 0.2f * v);
      v = acc[mt][nt][1] + b_dc[c0 + 1]; o.y = f2bf(v > 0.f ? v : 0.2f * v);
      v = acc[mt][nt][2] + b_dc[c0 + 2]; o.z = f2bf(v > 0.f ? v : 0.2f * v);
      v = acc[mt][nt][3] + b_dc[c0 + 3]; o.w = f2bf(v > 0.f ? v : 0.2f * v);
      *(short4*)(ab + (size_t)(w0 + px) * 64 + c0) = o;
    }
  }
}

// ---------------------------------------------------------------------------
// Kernel 3: conv_out via MFMA. Fill = shifted bf16 copy from actT; epilogue
// bias + residual x -> out fp32 NCHW.
// Grid (2,128,8), 256 threads.
// ---------------------------------------------------------------------------
__global__ __launch_bounds__(256) void k_conv_out(
    const short* __restrict__ actT, const short* __restrict__ wt_c,
    const float* __restrict__ b_c, const float* __restrict__ x,
    float* __restrict__ out) {
  __shared__ short val[64][296];
  const int b = blockIdx.z, h = blockIdx.y, w0 = blockIdx.x * 64;
  const int tid = threadIdx.x;
  const int wave = tid >> 6, lane = tid & 63, quad = lane >> 4, lr = lane & 15;
  const short* ab = actT + (size_t)b * HWn * 64;

  floatx4 zf = {0.f, 0.f, 0.f, 0.f};
  floatx4 acc[2][2] = {{zf, zf}, {zf, zf}};
  const int m0 = (wave & 1) * 32;
  const int n0 = (wave >> 1) * 32;

  for (int cc = 0; cc < 2; ++cc) {
    __syncthreads();
    for (int j = tid; j < 2304; j += 256) {
      int c8 = (j & 3) * 8;
      int px = (j >> 2) & 63;
      int kk = j >> 8;
      int ky = kk / 3, kx = kk - ky * 3;
      int gy = h + ky - 1, gx = w0 + px + kx - 1;
      short8 v = {0, 0, 0, 0, 0, 0, 0, 0};
      if (gy >= 0 && gy < Hn && gx >= 0 && gx < Wn)
        v = *(const short8*)(ab + (size_t)(gy * Wn + gx) * 64 + cc * 32 + c8);
      *(short8*)&val[px][kk * 32 + c8] = v;
    }
    __syncthreads();
    const short* wbase = wt_c + cc * 32 + quad * 8;
#pragma unroll
    for (int kk = 0; kk < 9; ++kk) {
      short8 a0 = *(const short8*)(wbase + (m0 + lr) * 576 + kk * 64);
      short8 a1 = *(const short8*)(wbase + (m0 + 16 + lr) * 576 + kk * 64);
      short8 bf0 = *(const short8*)&val[n0 + lr][kk * 32 + quad * 8];
      short8 bf1 = *(const short8*)&val[n0 + 16 + lr][kk * 32 + quad * 8];
      acc[0][0] = __builtin_amdgcn_mfma_f32_16x16x32_bf16(a0, bf0, acc[0][0], 0, 0, 0);
      acc[0][1] = __builtin_amdgcn_mfma_f32_16x16x32_bf16(a0, bf1, acc[0][1], 0, 0, 0);
      acc[1][0] = __builtin_amdgcn_mfma_f32_16x16x32_bf16(a1, bf0, acc[1][0], 0, 0, 0);
      acc[1][1] = __builtin_amdgcn_mfma_f32_16x16x32_bf16(a1, bf1, acc[1][1], 0, 0, 0);
    }
  }

#pragma unroll
  for (int mt = 0; mt < 2; ++mt) {
#pragma unroll
    for (int nt = 0; nt < 2; ++nt) {
      int px = n0 + nt * 16 + lr;
#pragma unroll
      for (int r = 0; r < 4; ++r) {
        int cout = m0 + mt * 16 + quad * 4 + r;
        size_t gidx = ((size_t)(b * 64 + cout) * Hn + h) * Wn + w0 + px;
        out[gidx] = acc[mt][nt][r] + b_c[cout] + x[gidx];
      }
    }
  }
}

// ---------------------------------------------------------------------------
extern "C" void kernel_launch(void* const* d_in, const int* in_sizes, int n_in,
                              void* d_out, int out_size, void* d_ws,
                              size_t ws_size, hipStream_t stream) {
  const float* x = (const float*)d_in[0];
  const float* w_om = (const float*)d_in[1];
  const float* b_om = (const float*)d_in[2];
  const float* w_dc = (const float*)d_in[3];
  const float* b_dc = (const float*)d_in[4];
  const float* w_c = (const float*)d_in[5];
  const float* b_c = (const float*)d_in[6];
  float* out = (float*)d_out;

  // ws layout: offmask fp32 (14.2 MB) | xT bf16 (16.8 MB) | actT bf16
  // (16.8 MB) | weights bf16 (184 KB)  -> ~48 MB total
  float* offmask = (float*)d_ws;
  short* xT = (short*)(offmask + (size_t)Bn * Kn * 3 * HWn);
  short* actT = xT + (size_t)Bn * HWn * 64;
  short* wt = actT + (size_t)Bn * HWn * 64;

  k_prep_w<<<dim3((160 * 576 + 255) / 256), 256, 0, stream>>>(w_om, w_dc, w_c, wt);
  k_prep_x<<<dim3(Hn, Bn), 256, 0, stream>>>(x, xT);
  k_conv_om<<<dim3(2, Hn, Bn), 256, 0, stream>>>(xT, wt, b_om, offmask);
  k_deform<<<dim3(2, Hn, Bn), 256, 0, stream>>>(xT, offmask, wt + 32 * 576, b_dc, actT);
  k_conv_out<<<dim3(2, Hn, Bn), 256, 0, stream>>>(actT, wt + 96 * 576, b_c, x, out);
}